// Round 6
// baseline (141.589 us; speedup 1.0000x reference)
//
#include <hip/hip_runtime.h>
#include <stdint.h>

#define KN 9
#define CC 128
#define FF 128
#define TM 32      // pixels per block (half an image row)
#define NT 512     // threads per block (8 waves)
#define LDK 136    // padded LDS K-stride (bf16); 272 B row, 16B-aligned

typedef __bf16 bf16x8 __attribute__((ext_vector_type(8)));
typedef float f32x4 __attribute__((ext_vector_type(4)));
typedef unsigned short us8 __attribute__((ext_vector_type(8)));

__constant__ float c_init_i[KN] = {0.f,0.f,1.f,2.f,2.f,1.f,0.f,2.f,1.f};
__constant__ float c_init_j[KN] = {0.f,1.f,1.f,2.f,0.f,2.f,1.f,0.f,2.f};

static __device__ inline float bf2f(unsigned short u) {
    union { unsigned u; float f; } v; v.u = ((unsigned)u) << 16; return v.f;
}

// Merged prep: blocks 0..143 transpose W; blocks 144..2191 convert x to bf16.
// Wt bf16 fragment-linear layout: frag slot s = (n*4+ks)*8 + nt (nt = f>>4),
// elem = s*512 + quad*128 + col*8 + e, with f = nt*16 + col, c = ks*32+quad*8+e.
// Each wave's B-frag is one contiguous 1KB chunk (lane*16B): perfectly
// coalesced direct-from-L2 register loads in deform_kernel.
__global__ void prep_kernel(const float* __restrict__ Wk, unsigned short* __restrict__ Wt,
                            const float* __restrict__ x, unsigned short* __restrict__ xb) {
    __shared__ unsigned short t[32][33];
    const int tid = threadIdx.x;
    if (blockIdx.x >= 144) {
        int i = ((blockIdx.x - 144) * 256 + tid) * 8;
        float4 a = *(const float4*)(x + i);
        float4 b = *(const float4*)(x + i + 4);
        us8 o;
        o[0] = __builtin_bit_cast(unsigned short, (__bf16)a.x);
        o[1] = __builtin_bit_cast(unsigned short, (__bf16)a.y);
        o[2] = __builtin_bit_cast(unsigned short, (__bf16)a.z);
        o[3] = __builtin_bit_cast(unsigned short, (__bf16)a.w);
        o[4] = __builtin_bit_cast(unsigned short, (__bf16)b.x);
        o[5] = __builtin_bit_cast(unsigned short, (__bf16)b.y);
        o[6] = __builtin_bit_cast(unsigned short, (__bf16)b.z);
        o[7] = __builtin_bit_cast(unsigned short, (__bf16)b.w);
        *(us8*)(xb + i) = o;
        return;
    }
    const int n  = blockIdx.x >> 4;
    const int tf = blockIdx.x & 3;        // f-tile (2 nt slices)
    const int tc = (blockIdx.x >> 2) & 3; // c-tile (ks)
    const int g  = tid >> 5;
    const int l  = tid & 31;
#pragma unroll
    for (int r = 0; r < 4; ++r) {
        int cl = g * 4 + r;
        t[cl][l] = __builtin_bit_cast(unsigned short,
                    (__bf16)Wk[(n << 14) + ((tc * 32 + cl) << 7) + (tf * 32 + l)]);
    }
    __syncthreads();
#pragma unroll
    for (int r = 0; r < 4; ++r) {
        int o   = r * 256 + tid;          // 0..1023 within this (n,ks,tf) tile
        int b   = o >> 9;                 // nt = tf*2 + b
        int q   = (o >> 7) & 3;
        int col = (o >> 3) & 15;
        int e   = o & 7;
        Wt[(((n * 4 + tc) * 4 + tf) << 10) + o] = t[q * 8 + e][b * 16 + col];
    }
}

// issue 4 corner loads (8 bf16 channels each) into NAMED us8 regs
#define ISSUE(n_, S) do {                                              \
    int lt_o = cB[ip][n_][0], rb_o = cB[ip][n_][1];                    \
    int rt_o = (rb_o & 0x7E000) | (lt_o & 0x1F80);                     \
    int lb_o = (lt_o & 0x7E000) | (rb_o & 0x1F80);                     \
    lt##S = *(const us8*)(bb16 + lt_o + icg);                          \
    rt##S = *(const us8*)(bb16 + rt_o + icg);                          \
    lb##S = *(const us8*)(bb16 + lb_o + icg);                          \
    rb##S = *(const us8*)(bb16 + rb_o + icg);                          \
    __builtin_amdgcn_sched_barrier(0);                                 \
  } while (0)

// bilinear interp of 8 channels + bf16 pack + one ds_write_b128
#define CONSUME(n_, S, d_) do {                                        \
    float fy_ = cF[ip][n_][0], fx_ = cF[ip][n_][1];                    \
    us8 pk_;                                                           \
    _Pragma("unroll")                                                  \
    for (int j = 0; j < 8; ++j) {                                      \
      float v0_ = bf2f(lt##S[j]), v1_ = bf2f(rt##S[j]);                \
      float v2_ = bf2f(lb##S[j]), v3_ = bf2f(rb##S[j]);                \
      float vt_ = v0_ + (v1_ - v0_) * fy_;                             \
      float vb_ = v2_ + (v3_ - v2_) * fy_;                             \
      float r_  = vt_ + (vb_ - vt_) * fx_;                             \
      pk_[j] = __builtin_bit_cast(unsigned short, (__bf16)r_);         \
    }                                                                  \
    *(us8*)&As[d_][ip][icg] = pk_;                                     \
  } while (0)

// 4 B-fragments for tap n_ (this wave's 16-filter slice), direct from L2
#define LOADB(n_) do {                                                 \
    bfr0 = *(const us8*)(wbase + ((n_) << 14));                        \
    bfr1 = *(const us8*)(wbase + ((n_) << 14) + 4096);                 \
    bfr2 = *(const us8*)(wbase + ((n_) << 14) + 8192);                 \
    bfr3 = *(const us8*)(wbase + ((n_) << 14) + 12288);                \
    __builtin_amdgcn_sched_barrier(0);                                 \
  } while (0)

#define MSTEP(d_, ks_, B_) do {                                        \
    bf16x8 a0_ = __builtin_bit_cast(bf16x8, *(const us8*)(&As[d_][col][(ks_) * 32 + quad * 8]));      \
    bf16x8 a1_ = __builtin_bit_cast(bf16x8, *(const us8*)(&As[d_][16 + col][(ks_) * 32 + quad * 8])); \
    acc0 = __builtin_amdgcn_mfma_f32_16x16x32_bf16(a0_, __builtin_bit_cast(bf16x8, B_), acc0, 0, 0, 0); \
    acc1 = __builtin_amdgcn_mfma_f32_16x16x32_bf16(a1_, __builtin_bit_cast(bf16x8, B_), acc1, 0, 0, 0); \
  } while (0)

#define MTAP(d_) do {                                                  \
    MSTEP(d_, 0, bfr0); MSTEP(d_, 1, bfr1);                            \
    MSTEP(d_, 2, bfr2); MSTEP(d_, 3, bfr3);                            \
  } while (0)

// lgkm-only barrier: drains ds_writes (As ready) and proves prior MFMA
// ds_reads done; global loads (gathers + B-frags) stay in flight across it.
#define BAR() do {                                                     \
    asm volatile("s_waitcnt lgkmcnt(0)" ::: "memory");                 \
    __builtin_amdgcn_s_barrier();                                      \
  } while (0)

__launch_bounds__(NT, 6)   // 85-VGPR cap: 3 blocks/CU = 6 waves/SIMD
__global__ void deform_kernel(const unsigned short* __restrict__ xb,
                              const float* __restrict__ off,
                              const unsigned short* __restrict__ Wt,
                              const float* __restrict__ bias,
                              float* __restrict__ out) {
    __shared__ unsigned short As[2][TM][LDK];  // double-buffered: 17408 B
    __shared__ int   cB[TM][KN][2];            // packed lt/rb offsets: 2304 B
    __shared__ float cF[TM][KN][2];            // (fy, fx): 2304 B
    // total 22016 B -> 3 blocks/CU (VGPR-capped at 85)

    const int tid = threadIdx.x;
    const int bb   = blockIdx.x & 7;           // XCD swizzle: image b -> XCD b
    const int rr   = blockIdx.x >> 3;          // 0..127: 32-pixel chunk in image
    const int pix0 = (bb << 12) + (rr << 5);

    // ---- phase 0: packed corner offsets + fractions per (p, n) ----
    for (int t = tid; t < TM * KN; t += NT) {   // 288 < 512: one pass
        int p = t & (TM - 1);
        int n = t >> 5;
        int pg = (rr << 5) + p;                 // pixel index within image
        float2 o = *(const float2*)(off + (size_t)(pix0 + p) * (2 * KN) + 2 * n);
        float y = (float)((pg >> 6) - 1) + c_init_i[n] + o.x;
        float x = (float)((pg & 63) - 1) + c_init_j[n] + o.y;
        y = fminf(fmaxf(y, 0.f), 63.f);
        x = fminf(fmaxf(x, 0.f), 63.f);
        float y0f = floorf(y), x0f = floorf(x);
        int y0 = (int)y0f, x0 = (int)x0f;
        int y1 = (int)ceilf(y), x1 = (int)ceilf(x);
        cB[p][n][0] = (y0 << 13) | (x0 << 7);   // lt element offset
        cB[p][n][1] = (y1 << 13) | (x1 << 7);   // rb element offset
        cF[p][n][0] = y - y0f;
        cF[p][n][1] = x - x0f;
    }

    const int wave = tid >> 6;                  // = nt slice (16 filters)
    const int lane = tid & 63;
    const int quad = lane >> 4;
    const int col  = lane & 15;

    f32x4 acc0 = {0.f,0.f,0.f,0.f}, acc1 = {0.f,0.f,0.f,0.f};

    const unsigned short* bb16  = xb + ((size_t)bb << 19);
    const unsigned short* wbase = Wt + (wave << 9) + (lane << 3);

    // gather: 1 item/thread/tap: pixel ip = tid>>4, channels icg..icg+7
    const int ip  = tid >> 4;
    const int icg = (tid & 15) * 8;

    us8 ltA, rtA, lbA, rbA;      // rolling gather sets (tap parity)
    us8 ltB, rtB, lbB, rbB;
    us8 bfr0, bfr1, bfr2, bfr3;  // this tap's B-fragments

    __syncthreads();   // coords ready

    ISSUE(0, A);
    LOADB(0);

    for (int n = 0; n < 8; n += 2) {
        // ---- tap n (even): buffer 0, gathers in set A ----
        ISSUE(n + 1, B);
        CONSUME(n, A, 0);
        BAR();
        MTAP(0);            // vmcnt waits only on LOADB(n); B-gathers fly on
        LOADB(n + 1);
        // ---- tap n+1 (odd): buffer 1, gathers in set B ----
        ISSUE(n + 2, A);
        CONSUME(n + 1, B, 1);
        BAR();
        MTAP(1);
        LOADB(n + 2);
        // As[0] rewritten next iteration only after this BAR (all waves'
        // MTAP(0) ds_reads lgkm-drained before it). Safe with 1 bar/tap.
    }
    // ---- tap 8: buffer 0, set A (issued at n=6) ----
    CONSUME(8, A, 0);
    BAR();
    MTAP(0);

    // ---- epilogue: C/D col=lane&15 -> filter, row=quad*4+reg -> pixel ----
    const int fcol = (wave << 4) + col;
    const float bv = bias[fcol];
#pragma unroll
    for (int r = 0; r < 2; ++r) {
        const f32x4 ac = r ? acc1 : acc0;
#pragma unroll
        for (int g = 0; g < 4; ++g) {
            int pr = pix0 + (r << 4) + (quad << 2) + g;
            out[(size_t)pr * FF + fcol] = ac[g] + bv;
        }
    }
}

extern "C" void kernel_launch(void* const* d_in, const int* in_sizes, int n_in,
                              void* d_out, int out_size, void* d_ws, size_t ws_size,
                              hipStream_t stream) {
    const float* x    = (const float*)d_in[0];
    const float* off  = (const float*)d_in[1];
    const float* Wk   = (const float*)d_in[2];
    const float* bias = (const float*)d_in[3];
    float* out = (float*)d_out;
    unsigned short* Wt = (unsigned short*)d_ws;            // 294912 B
    unsigned short* xb = (unsigned short*)d_ws + 147456;   // 8 MB bf16 x

    prep_kernel<<<144 + 2048, 256, 0, stream>>>(Wk, Wt, x, xb);
    deform_kernel<<<(8 * 64 * 64) / TM, NT, 0, stream>>>(xb, off, Wt, bias, out);
}

// Round 7
// 115.055 us; speedup vs baseline: 1.2306x; 1.2306x over previous
//
#include <hip/hip_runtime.h>
#include <stdint.h>

#define KN 9
#define CC 128
#define FF 128
#define TM 32      // pixels per block (half an image row)
#define NT 256     // threads per block (4 waves) -- small barrier domains
#define LDK 136    // padded LDS K-stride (bf16); 272 B row, 16B-aligned

typedef __bf16 bf16x8 __attribute__((ext_vector_type(8)));
typedef float f32x4 __attribute__((ext_vector_type(4)));
typedef unsigned short us8 __attribute__((ext_vector_type(8)));

__constant__ float c_init_i[KN] = {0.f,0.f,1.f,2.f,2.f,1.f,0.f,2.f,1.f};
__constant__ float c_init_j[KN] = {0.f,1.f,1.f,2.f,0.f,2.f,1.f,0.f,2.f};

static __device__ inline float bf2f(unsigned short u) {
    union { unsigned u; float f; } v; v.u = ((unsigned)u) << 16; return v.f;
}

// Merged prep: blocks 0..143 transpose W; blocks 144..2191 convert x to bf16.
// Wt bf16 fragment-linear layout: slot s = (n*4+ks)*8 + nt (nt = f>>4),
// elem = s*512 + quad*128 + col*8 + e, with f = nt*16 + col, c = ks*32+quad*8+e.
// Each wave's B-frag is one contiguous 1KB chunk (lane*16B): perfectly
// coalesced direct-from-L2 register loads in deform_kernel.
__global__ void prep_kernel(const float* __restrict__ Wk, unsigned short* __restrict__ Wt,
                            const float* __restrict__ x, unsigned short* __restrict__ xb) {
    __shared__ unsigned short t[32][33];
    const int tid = threadIdx.x;
    if (blockIdx.x >= 144) {
        int i = ((blockIdx.x - 144) * 256 + tid) * 8;
        float4 a = *(const float4*)(x + i);
        float4 b = *(const float4*)(x + i + 4);
        us8 o;
        o[0] = __builtin_bit_cast(unsigned short, (__bf16)a.x);
        o[1] = __builtin_bit_cast(unsigned short, (__bf16)a.y);
        o[2] = __builtin_bit_cast(unsigned short, (__bf16)a.z);
        o[3] = __builtin_bit_cast(unsigned short, (__bf16)a.w);
        o[4] = __builtin_bit_cast(unsigned short, (__bf16)b.x);
        o[5] = __builtin_bit_cast(unsigned short, (__bf16)b.y);
        o[6] = __builtin_bit_cast(unsigned short, (__bf16)b.z);
        o[7] = __builtin_bit_cast(unsigned short, (__bf16)b.w);
        *(us8*)(xb + i) = o;
        return;
    }
    const int n  = blockIdx.x >> 4;
    const int tf = blockIdx.x & 3;        // f-tile (2 nt slices)
    const int tc = (blockIdx.x >> 2) & 3; // c-tile (ks)
    const int g  = tid >> 5;
    const int l  = tid & 31;
#pragma unroll
    for (int r = 0; r < 4; ++r) {
        int cl = g * 4 + r;
        t[cl][l] = __builtin_bit_cast(unsigned short,
                    (__bf16)Wk[(n << 14) + ((tc * 32 + cl) << 7) + (tf * 32 + l)]);
    }
    __syncthreads();
#pragma unroll
    for (int r = 0; r < 4; ++r) {
        int o   = r * 256 + tid;          // 0..1023 within this (n,ks,tf) tile
        int b   = o >> 9;                 // nt = tf*2 + b
        int q   = (o >> 7) & 3;
        int col = (o >> 3) & 15;
        int e   = o & 7;
        Wt[(((n * 4 + tc) * 4 + tf) << 10) + o] = t[q * 8 + e][b * 16 + col];
    }
}

// issue 4 corner loads (8 bf16 channels) for pixel p_ into NAMED us8 regs
#define ISSUE(n_, p_, S) do {                                          \
    int lt_o = cB[p_][n_][0], rb_o = cB[p_][n_][1];                    \
    int rt_o = (rb_o & 0x7E000) | (lt_o & 0x1F80);                     \
    int lb_o = (lt_o & 0x7E000) | (rb_o & 0x1F80);                     \
    lt##S = *(const us8*)(bb16 + lt_o + icg);                          \
    rt##S = *(const us8*)(bb16 + rt_o + icg);                          \
    lb##S = *(const us8*)(bb16 + lb_o + icg);                          \
    rb##S = *(const us8*)(bb16 + rb_o + icg);                          \
    __builtin_amdgcn_sched_barrier(0);                                 \
  } while (0)

// bilinear interp of 8 channels + bf16 pack + one ds_write_b128
#define CONSUME(n_, p_, S, d_) do {                                    \
    float fy_ = cF[p_][n_][0], fx_ = cF[p_][n_][1];                    \
    us8 pk_;                                                           \
    _Pragma("unroll")                                                  \
    for (int j = 0; j < 8; ++j) {                                      \
      float v0_ = bf2f(lt##S[j]), v1_ = bf2f(rt##S[j]);                \
      float v2_ = bf2f(lb##S[j]), v3_ = bf2f(rb##S[j]);                \
      float vt_ = v0_ + (v1_ - v0_) * fy_;                             \
      float vb_ = v2_ + (v3_ - v2_) * fy_;                             \
      float r_  = vt_ + (vb_ - vt_) * fx_;                             \
      pk_[j] = __builtin_bit_cast(unsigned short, (__bf16)r_);         \
    }                                                                  \
    *(us8*)&As[d_][p_][icg] = pk_;                                     \
  } while (0)

// 8 B-fragments for tap n_ (this wave's 32-filter slice), direct from L2
#define LOADB(n_) do {                                                 \
    bfr0 = *(const us8*)(wbase + ((n_) << 14));                        \
    bfr1 = *(const us8*)(wbase + ((n_) << 14) + 512);                  \
    bfr2 = *(const us8*)(wbase + ((n_) << 14) + 4096);                 \
    bfr3 = *(const us8*)(wbase + ((n_) << 14) + 4096 + 512);           \
    bfr4 = *(const us8*)(wbase + ((n_) << 14) + 8192);                 \
    bfr5 = *(const us8*)(wbase + ((n_) << 14) + 8192 + 512);           \
    bfr6 = *(const us8*)(wbase + ((n_) << 14) + 12288);                \
    bfr7 = *(const us8*)(wbase + ((n_) << 14) + 12288 + 512);          \
    __builtin_amdgcn_sched_barrier(0);                                 \
  } while (0)

#define MSTEP(d_, ks_, B0, B1) do {                                    \
    bf16x8 a0_ = __builtin_bit_cast(bf16x8, *(const us8*)(&As[d_][col][(ks_) * 32 + quad * 8]));      \
    bf16x8 a1_ = __builtin_bit_cast(bf16x8, *(const us8*)(&As[d_][16 + col][(ks_) * 32 + quad * 8])); \
    acc00 = __builtin_amdgcn_mfma_f32_16x16x32_bf16(a0_, __builtin_bit_cast(bf16x8, B0), acc00, 0, 0, 0); \
    acc01 = __builtin_amdgcn_mfma_f32_16x16x32_bf16(a0_, __builtin_bit_cast(bf16x8, B1), acc01, 0, 0, 0); \
    acc10 = __builtin_amdgcn_mfma_f32_16x16x32_bf16(a1_, __builtin_bit_cast(bf16x8, B0), acc10, 0, 0, 0); \
    acc11 = __builtin_amdgcn_mfma_f32_16x16x32_bf16(a1_, __builtin_bit_cast(bf16x8, B1), acc11, 0, 0, 0); \
  } while (0)

#define MTAP(d_) do {                                                  \
    MSTEP(d_, 0, bfr0, bfr1); MSTEP(d_, 1, bfr2, bfr3);                \
    MSTEP(d_, 2, bfr4, bfr5); MSTEP(d_, 3, bfr6, bfr7);                \
  } while (0)

// lgkm-only barrier: drains ds_writes (As ready) and proves prior MFMA
// ds_reads done; global loads (gathers + B-frags) stay in flight across it.
#define BAR() do {                                                     \
    asm volatile("s_waitcnt lgkmcnt(0)" ::: "memory");                 \
    __builtin_amdgcn_s_barrier();                                      \
  } while (0)

// Live-set budget: 2 gather sets (32) + bfr (32) + acc (16) + addr (~15)
// = ~95 VGPR.  launch_bounds(256,5) caps at 102 -> FITS (R6 failed because
// the same live set sat under an 85 cap and spilled to scratch).
__launch_bounds__(NT, 5)   // 5 waves/SIMD = 20 waves/CU = 5 blocks/CU
__global__ void deform_kernel(const unsigned short* __restrict__ xb,
                              const float* __restrict__ off,
                              const unsigned short* __restrict__ Wt,
                              const float* __restrict__ bias,
                              float* __restrict__ out) {
    __shared__ unsigned short As[2][TM][LDK];  // double-buffered: 17408 B
    __shared__ int   cB[TM][KN][2];            // packed lt/rb offsets: 2304 B
    __shared__ float cF[TM][KN][2];            // (fy, fx): 2304 B
    // total 22016 B; 5 blocks/CU -> 110 KB LDS of 160 KB

    const int tid = threadIdx.x;
    const int bb   = blockIdx.x & 7;           // XCD swizzle: image b -> XCD b
    const int rr   = blockIdx.x >> 3;          // 0..127: 32-pixel chunk
    const int pix0 = (bb << 12) + (rr << 5);

    // ---- phase 0: packed corner offsets + fractions per (p, n) ----
    for (int t = tid; t < TM * KN; t += NT) {   // 288 entries, 2 passes
        int p = t & (TM - 1);
        int n = t >> 5;
        int pg = (rr << 5) + p;                 // pixel index within image
        float2 o = *(const float2*)(off + (size_t)(pix0 + p) * (2 * KN) + 2 * n);
        float y = (float)((pg >> 6) - 1) + c_init_i[n] + o.x;
        float x = (float)((pg & 63) - 1) + c_init_j[n] + o.y;
        y = fminf(fmaxf(y, 0.f), 63.f);
        x = fminf(fmaxf(x, 0.f), 63.f);
        float y0f = floorf(y), x0f = floorf(x);
        int y0 = (int)y0f, x0 = (int)x0f;
        int y1 = (int)ceilf(y), x1 = (int)ceilf(x);
        cB[p][n][0] = (y0 << 13) | (x0 << 7);   // lt element offset
        cB[p][n][1] = (y1 << 13) | (x1 << 7);   // rb element offset
        cF[p][n][0] = y - y0f;
        cF[p][n][1] = x - x0f;
    }

    const int wave = tid >> 6;                  // 0..3: owns 32 filters
    const int lane = tid & 63;
    const int quad = lane >> 4;
    const int col  = lane & 15;

    f32x4 acc00 = {0.f,0.f,0.f,0.f}, acc01 = {0.f,0.f,0.f,0.f};
    f32x4 acc10 = {0.f,0.f,0.f,0.f}, acc11 = {0.f,0.f,0.f,0.f};

    const unsigned short* bb16  = xb + ((size_t)bb << 19);
    const unsigned short* wbase = Wt + (wave << 10) + (lane << 3);

    // gather: 2 items/thread/tap: pixels ip0, ip0+16; channels icg..icg+7
    const int ip0 = tid >> 4;          // 0..15
    const int ip1 = ip0 + 16;
    const int icg = (tid & 15) * 8;

    us8 ltA, rtA, lbA, rbA;      // item-0 set (cross-tap prefetched)
    us8 ltB, rtB, lbB, rbB;      // item-1 set
    us8 bfr0, bfr1, bfr2, bfr3, bfr4, bfr5, bfr6, bfr7;

    __syncthreads();   // coords ready

    ISSUE(0, ip0, A);  // prologue: tap 0, item 0
    int d = 0;

    for (int n = 0; n < KN; ++n, d ^= 1) {
        ISSUE(n, ip1, B);
        LOADB(n);                 // rides until MTAP (post-barrier)
        CONSUME(n, ip0, A, d);    // item 0 arrived during prior MFMA phase
        CONSUME(n, ip1, B, d);

        BAR();
        // Hazard: As[d] written above, read by MTAP below; As[d] is next
        // rewritten at tap n+2, after BAR(n+1) -- by which point every
        // wave's MTAP(n) ds_reads are lgkm-drained (its own BAR(n+1) wait).

        if (n + 1 < KN) ISSUE(n + 1, ip0, A);   // flies under MFMA phase

        MTAP(d);
    }

    // ---- epilogue: C/D col=lane&15 -> filter, row=quad*4+reg -> pixel ----
    const int fbase = (wave << 5);
#pragma unroll
    for (int b = 0; b < 2; ++b) {
        int f = fbase + b * 16 + col;
        float bv = bias[f];
        const f32x4 ac0 = b ? acc01 : acc00;
        const f32x4 ac1 = b ? acc11 : acc10;
#pragma unroll
        for (int r = 0; r < 4; ++r) {
            int pr0 = pix0 + (quad << 2) + r;
            out[(size_t)pr0 * FF + f] = ac0[r] + bv;
            int pr1 = pr0 + 16;
            out[(size_t)pr1 * FF + f] = ac1[r] + bv;
        }
    }
}

extern "C" void kernel_launch(void* const* d_in, const int* in_sizes, int n_in,
                              void* d_out, int out_size, void* d_ws, size_t ws_size,
                              hipStream_t stream) {
    const float* x    = (const float*)d_in[0];
    const float* off  = (const float*)d_in[1];
    const float* Wk   = (const float*)d_in[2];
    const float* bias = (const float*)d_in[3];
    float* out = (float*)d_out;
    unsigned short* Wt = (unsigned short*)d_ws;            // 294912 B
    unsigned short* xb = (unsigned short*)d_ws + 147456;   // 8 MB bf16 x

    prep_kernel<<<144 + 2048, 256, 0, stream>>>(Wk, Wt, x, xb);
    deform_kernel<<<(8 * 64 * 64) / TM, NT, 0, stream>>>(xb, off, Wt, bias, out);
}

// Round 9
// 99.521 us; speedup vs baseline: 1.4227x; 1.1561x over previous
//
#include <hip/hip_runtime.h>
#include <stdint.h>

#define KN 9
#define CC 128
#define FF 128
#define TM 64      // pixels per block (one full image row)
#define NT 512     // threads per block (8 waves)
#define LDK 136    // padded LDS K-stride (bf16); 272 B row, 16B-aligned

typedef __bf16 bf16x8 __attribute__((ext_vector_type(8)));
typedef float f32x4 __attribute__((ext_vector_type(4)));
typedef unsigned short us8 __attribute__((ext_vector_type(8)));

__constant__ float c_init_i[KN] = {0.f,0.f,1.f,2.f,2.f,1.f,0.f,2.f,1.f};
__constant__ float c_init_j[KN] = {0.f,1.f,1.f,2.f,0.f,2.f,1.f,0.f,2.f};

static __device__ inline float bf2f(unsigned short u) {
    union { unsigned u; float f; } v; v.u = ((unsigned)u) << 16; return v.f;
}

// Merged prep: blocks 0..143 transpose W; blocks 144..2191 convert x to bf16.
// W (KN, C, F) fp32 -> Wt bf16 in WAVE-LINEAR fragment layout:
//   elem = slot*512 + quad*128 + col*8 + e,  slot = ((n*4+ks)*4+g)*2 + b
//   f = g*32 + b*16 + col, c = ks*32 + quad*8 + e
// Each wave's B-frag is a contiguous 1KB chunk (lane*8 elems): perfectly
// coalesced direct-from-L2 register loads in deform_kernel.
__global__ void prep_kernel(const float* __restrict__ Wk, unsigned short* __restrict__ Wt,
                            const float* __restrict__ x, unsigned short* __restrict__ xb) {
    __shared__ unsigned short t[32][33];
    const int tid = threadIdx.x;
    if (blockIdx.x >= 144) {
        int i = ((blockIdx.x - 144) * 256 + tid) * 8;
        float4 a = *(const float4*)(x + i);
        float4 b = *(const float4*)(x + i + 4);
        us8 o;
        o[0] = __builtin_bit_cast(unsigned short, (__bf16)a.x);
        o[1] = __builtin_bit_cast(unsigned short, (__bf16)a.y);
        o[2] = __builtin_bit_cast(unsigned short, (__bf16)a.z);
        o[3] = __builtin_bit_cast(unsigned short, (__bf16)a.w);
        o[4] = __builtin_bit_cast(unsigned short, (__bf16)b.x);
        o[5] = __builtin_bit_cast(unsigned short, (__bf16)b.y);
        o[6] = __builtin_bit_cast(unsigned short, (__bf16)b.z);
        o[7] = __builtin_bit_cast(unsigned short, (__bf16)b.w);
        *(us8*)(xb + i) = o;
        return;
    }
    const int n  = blockIdx.x >> 4;
    const int tf = blockIdx.x & 3;        // f-tile (g)
    const int tc = (blockIdx.x >> 2) & 3; // c-tile (ks)
    const int g  = tid >> 5;
    const int l  = tid & 31;
#pragma unroll
    for (int r = 0; r < 4; ++r) {
        int cl = g * 4 + r;
        t[cl][l] = __builtin_bit_cast(unsigned short,
                    (__bf16)Wk[(n << 14) + ((tc * 32 + cl) << 7) + (tf * 32 + l)]);
    }
    __syncthreads();
#pragma unroll
    for (int r = 0; r < 4; ++r) {
        int o   = r * 256 + tid;          // 0..1023 within this (n,ks,g) tile
        int b   = o >> 9;
        int q   = (o >> 7) & 3;
        int col = (o >> 3) & 15;
        int e   = o & 7;
        Wt[(((n * 4 + tc) * 4 + tf) << 10) + o] = t[q * 8 + e][b * 16 + col];
    }
}

// issue 4 corner loads (8 bf16 channels each) into NAMED us8 regs
#define ISSUE(n_, s_, S) do {                                          \
    int p_ = (s_) >> 4; int ch_ = ((s_) & 15) * 8;                     \
    int lt_o = cB[p_][n_][0], rb_o = cB[p_][n_][1];                    \
    int rt_o = (rb_o & 0x7E000) | (lt_o & 0x1F80);                     \
    int lb_o = (lt_o & 0x7E000) | (rb_o & 0x1F80);                     \
    lt##S = *(const us8*)(bb16 + lt_o + ch_);                          \
    rt##S = *(const us8*)(bb16 + rt_o + ch_);                          \
    lb##S = *(const us8*)(bb16 + lb_o + ch_);                          \
    rb##S = *(const us8*)(bb16 + rb_o + ch_);                          \
    __builtin_amdgcn_sched_barrier(0);                                 \
  } while (0)

// bilinear interp of 8 channels + bf16 pack + one ds_write_b128
#define CONSUME(n_, s_, S) do {                                        \
    int p_ = (s_) >> 4; int ch_ = ((s_) & 15) * 8;                     \
    float fy_ = cF[p_][n_][0], fx_ = cF[p_][n_][1];                    \
    us8 pk_;                                                           \
    _Pragma("unroll")                                                  \
    for (int j = 0; j < 8; ++j) {                                      \
      float v0_ = bf2f(lt##S[j]), v1_ = bf2f(rt##S[j]);                \
      float v2_ = bf2f(lb##S[j]), v3_ = bf2f(rb##S[j]);                \
      float vt_ = v0_ + (v1_ - v0_) * fy_;                             \
      float vb_ = v2_ + (v3_ - v2_) * fy_;                             \
      float r_  = vt_ + (vb_ - vt_) * fx_;                             \
      pk_[j] = __builtin_bit_cast(unsigned short, (__bf16)r_);         \
    }                                                                  \
    *(us8*)&As[d][p_][ch_] = pk_;                                      \
  } while (0)

// B-fragment loads for tap n_, direct from L2, fully coalesced (1KB/wave/frag)
#define LOADB(n_) do {                                                 \
    const unsigned short* wn_ = wbase + ((n_) << 14);                  \
    bfr0 = *(const us8*)(wn_);                                         \
    bfr1 = *(const us8*)(wn_ + 512);                                   \
    bfr2 = *(const us8*)(wn_ + 4096);                                  \
    bfr3 = *(const us8*)(wn_ + 4096 + 512);                            \
    bfr4 = *(const us8*)(wn_ + 8192);                                  \
    bfr5 = *(const us8*)(wn_ + 8192 + 512);                            \
    bfr6 = *(const us8*)(wn_ + 12288);                                 \
    bfr7 = *(const us8*)(wn_ + 12288 + 512);                           \
    __builtin_amdgcn_sched_barrier(0);                                 \
  } while (0)

#define MSTEP(ks_, B0, B1) do {                                        \
    bf16x8 a0_ = __builtin_bit_cast(bf16x8, *(const us8*)(&As[d][mtile + col][(ks_) * 32 + quad * 8]));      \
    bf16x8 a1_ = __builtin_bit_cast(bf16x8, *(const us8*)(&As[d][mtile + 16 + col][(ks_) * 32 + quad * 8])); \
    acc00 = __builtin_amdgcn_mfma_f32_16x16x32_bf16(a0_, __builtin_bit_cast(bf16x8, B0), acc00, 0, 0, 0);    \
    acc01 = __builtin_amdgcn_mfma_f32_16x16x32_bf16(a0_, __builtin_bit_cast(bf16x8, B1), acc01, 0, 0, 0);    \
    acc10 = __builtin_amdgcn_mfma_f32_16x16x32_bf16(a1_, __builtin_bit_cast(bf16x8, B0), acc10, 0, 0, 0);    \
    acc11 = __builtin_amdgcn_mfma_f32_16x16x32_bf16(a1_, __builtin_bit_cast(bf16x8, B1), acc11, 0, 0, 0);    \
  } while (0)

__launch_bounds__(NT, 4)   // 128 VGPR cap: 2 blocks/CU. Measured (R6/R7):
                           // any tighter cap spills the cross-barrier live set.
__global__ void deform_kernel(const unsigned short* __restrict__ xb,
                              const float* __restrict__ off,
                              const unsigned short* __restrict__ Wt,
                              const float* __restrict__ bias,
                              float* __restrict__ out) {
    __shared__ unsigned short As[2][TM][LDK];  // double-buffered: 34816 B
    __shared__ int   cB[TM][KN][2];            // packed lt/rb offsets: 4608 B
    __shared__ float cF[TM][KN][2];            // (fy, fx): 4608 B
    // total 44032 B -> 2 blocks/CU (VGPR-capped)

    const int tid = threadIdx.x;
    const int bb   = blockIdx.x & 7;           // XCD swizzle: image b -> XCD b
    const int hh   = blockIdx.x >> 3;
    const int pix0 = (bb << 12) + (hh << 6);

    // ---- phase 0: packed corner offsets + fractions per (p, n) ----
    for (int t = tid; t < TM * KN; t += NT) {
        int p = t & (TM - 1);
        int n = t >> 6;
        float2 o = *(const float2*)(off + (size_t)(pix0 + p) * (2 * KN) + 2 * n);
        float y = (float)(hh - 1) + c_init_i[n] + o.x;
        float x = (float)(p - 1) + c_init_j[n] + o.y;
        y = fminf(fmaxf(y, 0.f), 63.f);
        x = fminf(fmaxf(x, 0.f), 63.f);
        float y0f = floorf(y), x0f = floorf(x);
        int y0 = (int)y0f, x0 = (int)x0f;
        int y1 = (int)ceilf(y), x1 = (int)ceilf(x);
        cB[p][n][0] = (y0 << 13) | (x0 << 7);   // lt element offset
        cB[p][n][1] = (y1 << 13) | (x1 << 7);   // rb element offset
        cF[p][n][0] = y - y0f;
        cF[p][n][1] = x - x0f;
    }

    const int wave = tid >> 6;
    const int lane = tid & 63;
    const int quad = lane >> 4;
    const int col  = lane & 15;
    const int mtile = (wave & 1) * 32;
    const int ntile = (wave >> 1) * 32;
    const int gi    = wave >> 1;

    f32x4 acc00 = {0.f,0.f,0.f,0.f}, acc01 = {0.f,0.f,0.f,0.f};
    f32x4 acc10 = {0.f,0.f,0.f,0.f}, acc11 = {0.f,0.f,0.f,0.f};

    const unsigned short* bb16  = xb + ((size_t)bb << 19);
    const unsigned short* wbase = Wt + (gi << 10) + (lane << 3);

    us8 ltA, rtA, lbA, rbA;
    us8 ltB, rtB, lbB, rbB;
    us8 bfr0, bfr1, bfr2, bfr3, bfr4, bfr5, bfr6, bfr7;

    __syncthreads();   // coords ready

    ISSUE(0, tid, A);  // prologue: tap 0, item 0
    int d = 0;

    for (int n = 0; n < KN; ++n, d ^= 1) {
        ISSUE(n, tid + NT, B);   // item 1 gathers first (critical path)
        LOADB(n);                // B frags ride until MSTEP (post-barrier)
        CONSUME(n, tid, A);
        ISSUE(n + 1 < KN ? n + 1 : n, tid, A);  // next tap item 0: flies over
                                                 // barrier + MFMA phase
        CONSUME(n, tid + NT, B);

        // ONE barrier per tap: lgkmcnt(0) drains our ds_writes to As[d] AND
        // proves our MSTEP(n-1) ds_reads of As[d^1] completed; global loads
        // (gathers + bfr) stay in flight across the barrier.
        asm volatile("s_waitcnt lgkmcnt(0)" ::: "memory");
        __builtin_amdgcn_s_barrier();
        // Hazard proof: wave W writes As[d^1] next tap; As[d] is rewritten only
        // at tap n+2, which is after barrier(n+1); every wave's tap-n reads of
        // As[d] completed before it reached barrier(n+1) (lgkmcnt(0)). Safe.

        MSTEP(0, bfr0, bfr1);
        MSTEP(1, bfr2, bfr3);
        MSTEP(2, bfr4, bfr5);
        MSTEP(3, bfr6, bfr7);
    }

    // ---- epilogue: C/D layout col=lane&15, row=quad*4+reg (HW-verified) ----
#pragma unroll
    for (int b = 0; b < 2; ++b) {
        int f = ntile + b * 16 + col;
        float bv = bias[f];
        const f32x4 ac0 = b ? acc01 : acc00;
        const f32x4 ac1 = b ? acc11 : acc10;
#pragma unroll
        for (int r = 0; r < 4; ++r) {
            int pr0 = pix0 + mtile + quad * 4 + r;
            out[(size_t)pr0 * FF + f] = ac0[r] + bv;
            int pr1 = pr0 + 16;
            out[(size_t)pr1 * FF + f] = ac1[r] + bv;
        }
    }
}

extern "C" void kernel_launch(void* const* d_in, const int* in_sizes, int n_in,
                              void* d_out, int out_size, void* d_ws, size_t ws_size,
                              hipStream_t stream) {
    const float* x    = (const float*)d_in[0];
    const float* off  = (const float*)d_in[1];
    const float* Wk   = (const float*)d_in[2];
    const float* bias = (const float*)d_in[3];
    float* out = (float*)d_out;
    unsigned short* Wt = (unsigned short*)d_ws;            // 294912 B
    unsigned short* xb = (unsigned short*)d_ws + 147456;   // 8 MB bf16 x

    prep_kernel<<<144 + 2048, 256, 0, stream>>>(Wk, Wt, x, xb);
    deform_kernel<<<(8 * 64 * 64) / TM, NT, 0, stream>>>(xb, off, Wt, bias, out);
}

// Round 10
// 98.780 us; speedup vs baseline: 1.4334x; 1.0075x over previous
//
#include <hip/hip_runtime.h>
#include <stdint.h>

#define KN 9
#define CC 128
#define FF 128
#define TM 32      // pixels per block (half an image row)
#define NT 256     // threads per block (4 waves) -- small barrier domains
#define LDK 136    // padded LDS K-stride (bf16); 272 B row, 16B-aligned

typedef __bf16 bf16x8 __attribute__((ext_vector_type(8)));
typedef float f32x4 __attribute__((ext_vector_type(4)));
typedef unsigned short us8 __attribute__((ext_vector_type(8)));

__constant__ float c_init_i[KN] = {0.f,0.f,1.f,2.f,2.f,1.f,0.f,2.f,1.f};
__constant__ float c_init_j[KN] = {0.f,1.f,1.f,2.f,0.f,2.f,1.f,0.f,2.f};

static __device__ inline float bf2f(unsigned short u) {
    union { unsigned u; float f; } v; v.u = ((unsigned)u) << 16; return v.f;
}

// Merged prep: blocks 0..143 transpose W; blocks 144..2191 convert x to bf16.
// Wt bf16 fragment-linear layout: slot s = (n*4+ks)*8 + nt (nt = f>>4),
// elem = s*512 + quad*128 + col*8 + e, with f = nt*16 + col, c = ks*32+quad*8+e.
// Each wave's B-frag is one contiguous 1KB chunk (lane*16B): perfectly
// coalesced direct-from-L2 register loads in deform_kernel.
__global__ void prep_kernel(const float* __restrict__ Wk, unsigned short* __restrict__ Wt,
                            const float* __restrict__ x, unsigned short* __restrict__ xb) {
    __shared__ unsigned short t[32][33];
    const int tid = threadIdx.x;
    if (blockIdx.x >= 144) {
        int i = ((blockIdx.x - 144) * 256 + tid) * 8;
        float4 a = *(const float4*)(x + i);
        float4 b = *(const float4*)(x + i + 4);
        us8 o;
        o[0] = __builtin_bit_cast(unsigned short, (__bf16)a.x);
        o[1] = __builtin_bit_cast(unsigned short, (__bf16)a.y);
        o[2] = __builtin_bit_cast(unsigned short, (__bf16)a.z);
        o[3] = __builtin_bit_cast(unsigned short, (__bf16)a.w);
        o[4] = __builtin_bit_cast(unsigned short, (__bf16)b.x);
        o[5] = __builtin_bit_cast(unsigned short, (__bf16)b.y);
        o[6] = __builtin_bit_cast(unsigned short, (__bf16)b.z);
        o[7] = __builtin_bit_cast(unsigned short, (__bf16)b.w);
        *(us8*)(xb + i) = o;
        return;
    }
    const int n  = blockIdx.x >> 4;
    const int tf = blockIdx.x & 3;        // f-tile (2 nt slices)
    const int tc = (blockIdx.x >> 2) & 3; // c-tile (ks)
    const int g  = tid >> 5;
    const int l  = tid & 31;
#pragma unroll
    for (int r = 0; r < 4; ++r) {
        int cl = g * 4 + r;
        t[cl][l] = __builtin_bit_cast(unsigned short,
                    (__bf16)Wk[(n << 14) + ((tc * 32 + cl) << 7) + (tf * 32 + l)]);
    }
    __syncthreads();
#pragma unroll
    for (int r = 0; r < 4; ++r) {
        int o   = r * 256 + tid;          // 0..1023 within this (n,ks,tf) tile
        int b   = o >> 9;                 // nt = tf*2 + b
        int q   = (o >> 7) & 3;
        int col = (o >> 3) & 15;
        int e   = o & 7;
        Wt[(((n * 4 + tc) * 4 + tf) << 10) + o] = t[q * 8 + e][b * 16 + col];
    }
}

// issue 4 corner loads (8 bf16 channels) for pixel p_ into NAMED us8 regs
#define ISSUE(n_, p_, S) do {                                          \
    int lt_o = cB[p_][n_][0], rb_o = cB[p_][n_][1];                    \
    int rt_o = (rb_o & 0x7E000) | (lt_o & 0x1F80);                     \
    int lb_o = (lt_o & 0x7E000) | (rb_o & 0x1F80);                     \
    lt##S = *(const us8*)(bb16 + lt_o + icg);                          \
    rt##S = *(const us8*)(bb16 + rt_o + icg);                          \
    lb##S = *(const us8*)(bb16 + lb_o + icg);                          \
    rb##S = *(const us8*)(bb16 + rb_o + icg);                          \
    __builtin_amdgcn_sched_barrier(0);                                 \
  } while (0)

// bilinear interp of 8 channels + bf16 pack + one ds_write_b128
#define CONSUME(n_, p_, S, d_) do {                                    \
    float fy_ = cF[p_][n_][0], fx_ = cF[p_][n_][1];                    \
    us8 pk_;                                                           \
    _Pragma("unroll")                                                  \
    for (int j = 0; j < 8; ++j) {                                      \
      float v0_ = bf2f(lt##S[j]), v1_ = bf2f(rt##S[j]);                \
      float v2_ = bf2f(lb##S[j]), v3_ = bf2f(rb##S[j]);                \
      float vt_ = v0_ + (v1_ - v0_) * fy_;                             \
      float vb_ = v2_ + (v3_ - v2_) * fy_;                             \
      float r_  = vt_ + (vb_ - vt_) * fx_;                             \
      pk_[j] = __builtin_bit_cast(unsigned short, (__bf16)r_);         \
    }                                                                  \
    *(us8*)&As[d_][p_][icg] = pk_;                                     \
  } while (0)

// 8 B-fragments for tap n_ (this wave's 32-filter slice), direct from L2
#define LOADB(n_) do {                                                 \
    bfr0 = *(const us8*)(wbase + ((n_) << 14));                        \
    bfr1 = *(const us8*)(wbase + ((n_) << 14) + 512);                  \
    bfr2 = *(const us8*)(wbase + ((n_) << 14) + 4096);                 \
    bfr3 = *(const us8*)(wbase + ((n_) << 14) + 4096 + 512);           \
    bfr4 = *(const us8*)(wbase + ((n_) << 14) + 8192);                 \
    bfr5 = *(const us8*)(wbase + ((n_) << 14) + 8192 + 512);           \
    bfr6 = *(const us8*)(wbase + ((n_) << 14) + 12288);                \
    bfr7 = *(const us8*)(wbase + ((n_) << 14) + 12288 + 512);          \
    __builtin_amdgcn_sched_barrier(0);                                 \
  } while (0)

#define MSTEP(d_, ks_, B0, B1) do {                                    \
    bf16x8 a0_ = __builtin_bit_cast(bf16x8, *(const us8*)(&As[d_][col][(ks_) * 32 + quad * 8]));      \
    bf16x8 a1_ = __builtin_bit_cast(bf16x8, *(const us8*)(&As[d_][16 + col][(ks_) * 32 + quad * 8])); \
    acc00 = __builtin_amdgcn_mfma_f32_16x16x32_bf16(a0_, __builtin_bit_cast(bf16x8, B0), acc00, 0, 0, 0); \
    acc01 = __builtin_amdgcn_mfma_f32_16x16x32_bf16(a0_, __builtin_bit_cast(bf16x8, B1), acc01, 0, 0, 0); \
    acc10 = __builtin_amdgcn_mfma_f32_16x16x32_bf16(a1_, __builtin_bit_cast(bf16x8, B0), acc10, 0, 0, 0); \
    acc11 = __builtin_amdgcn_mfma_f32_16x16x32_bf16(a1_, __builtin_bit_cast(bf16x8, B1), acc11, 0, 0, 0); \
  } while (0)

#define MTAP(d_) do {                                                  \
    MSTEP(d_, 0, bfr0, bfr1); MSTEP(d_, 1, bfr2, bfr3);                \
    MSTEP(d_, 2, bfr4, bfr5); MSTEP(d_, 3, bfr6, bfr7);                \
  } while (0)

// lgkm-only barrier: drains ds_writes (As ready) and proves prior MFMA
// ds_reads done; global loads (gathers + B-frags) stay in flight across it.
#define BAR() do {                                                     \
    asm volatile("s_waitcnt lgkmcnt(0)" ::: "memory");                 \
    __builtin_amdgcn_s_barrier();                                      \
  } while (0)

// Occupancy-matrix cell (NT=256, cap=128): 4 blocks/CU x 4 waves = 16
// waves/CU (same TLP as R5) but FOUR independent barrier domains -- when one
// block drains at its per-tap barrier, 12 waves keep issuing (vs 8 at NT=512).
// Caps 102 (R7) and 85 (R6) spilled; 128 never has (R1/R2/R5).
__launch_bounds__(NT, 4)
__global__ void deform_kernel(const unsigned short* __restrict__ xb,
                              const float* __restrict__ off,
                              const unsigned short* __restrict__ Wt,
                              const float* __restrict__ bias,
                              float* __restrict__ out) {
    __shared__ unsigned short As[2][TM][LDK];  // double-buffered: 8704 B
    __shared__ int   cB[TM][KN][2];            // packed lt/rb offsets: 2304 B
    __shared__ float cF[TM][KN][2];            // (fy, fx): 2304 B
    // total 22016 B; 4 blocks/CU -> 86 KB LDS of 160 KB

    const int tid = threadIdx.x;
    const int bb   = blockIdx.x & 7;           // XCD swizzle: image b -> XCD b
    const int rr   = blockIdx.x >> 3;          // 0..127: 32-pixel chunk
    const int pix0 = (bb << 12) + (rr << 5);

    // ---- phase 0: packed corner offsets + fractions per (p, n) ----
    for (int t = tid; t < TM * KN; t += NT) {   // 288 entries, 2 passes
        int p = t & (TM - 1);
        int n = t >> 5;
        int pg = (rr << 5) + p;                 // pixel index within image
        float2 o = *(const float2*)(off + (size_t)(pix0 + p) * (2 * KN) + 2 * n);
        float y = (float)((pg >> 6) - 1) + c_init_i[n] + o.x;
        float x = (float)((pg & 63) - 1) + c_init_j[n] + o.y;
        y = fminf(fmaxf(y, 0.f), 63.f);
        x = fminf(fmaxf(x, 0.f), 63.f);
        float y0f = floorf(y), x0f = floorf(x);
        int y0 = (int)y0f, x0 = (int)x0f;
        int y1 = (int)ceilf(y), x1 = (int)ceilf(x);
        cB[p][n][0] = (y0 << 13) | (x0 << 7);   // lt element offset
        cB[p][n][1] = (y1 << 13) | (x1 << 7);   // rb element offset
        cF[p][n][0] = y - y0f;
        cF[p][n][1] = x - x0f;
    }

    const int wave = tid >> 6;                  // 0..3: owns 32 filters
    const int lane = tid & 63;
    const int quad = lane >> 4;
    const int col  = lane & 15;

    f32x4 acc00 = {0.f,0.f,0.f,0.f}, acc01 = {0.f,0.f,0.f,0.f};
    f32x4 acc10 = {0.f,0.f,0.f,0.f}, acc11 = {0.f,0.f,0.f,0.f};

    const unsigned short* bb16  = xb + ((size_t)bb << 19);
    const unsigned short* wbase = Wt + (wave << 10) + (lane << 3);

    // gather: 2 items/thread/tap: pixels ip0, ip0+16; channels icg..icg+7
    const int ip0 = tid >> 4;          // 0..15
    const int ip1 = ip0 + 16;
    const int icg = (tid & 15) * 8;

    us8 ltA, rtA, lbA, rbA;      // item-0 set (cross-tap prefetched)
    us8 ltB, rtB, lbB, rbB;      // item-1 set
    us8 bfr0, bfr1, bfr2, bfr3, bfr4, bfr5, bfr6, bfr7;

    __syncthreads();   // coords ready

    ISSUE(0, ip0, A);  // prologue: tap 0, item 0
    int d = 0;

    for (int n = 0; n < KN; ++n, d ^= 1) {
        ISSUE(n, ip1, B);
        LOADB(n);                 // rides until MTAP (post-barrier)
        CONSUME(n, ip0, A, d);    // item 0 arrived during prior MFMA phase
        CONSUME(n, ip1, B, d);

        BAR();
        // Hazard: As[d] written above, read by MTAP below; As[d] is next
        // rewritten at tap n+2, after BAR(n+1) -- by which point every
        // wave's tap-n reads are lgkm-drained (its own BAR(n+1) wait).

        if (n + 1 < KN) ISSUE(n + 1, ip0, A);   // flies under MFMA phase

        MTAP(d);
    }

    // ---- epilogue: C/D col=lane&15 -> filter, row=quad*4+reg -> pixel ----
    const int fbase = (wave << 5);
#pragma unroll
    for (int b = 0; b < 2; ++b) {
        int f = fbase + b * 16 + col;
        float bv = bias[f];
        const f32x4 ac0 = b ? acc01 : acc00;
        const f32x4 ac1 = b ? acc11 : acc10;
#pragma unroll
        for (int r = 0; r < 4; ++r) {
            int pr0 = pix0 + (quad << 2) + r;
            out[(size_t)pr0 * FF + f] = ac0[r] + bv;
            int pr1 = pr0 + 16;
            out[(size_t)pr1 * FF + f] = ac1[r] + bv;
        }
    }
}

extern "C" void kernel_launch(void* const* d_in, const int* in_sizes, int n_in,
                              void* d_out, int out_size, void* d_ws, size_t ws_size,
                              hipStream_t stream) {
    const float* x    = (const float*)d_in[0];
    const float* off  = (const float*)d_in[1];
    const float* Wk   = (const float*)d_in[2];
    const float* bias = (const float*)d_in[3];
    float* out = (float*)d_out;
    unsigned short* Wt = (unsigned short*)d_ws;            // 294912 B
    unsigned short* xb = (unsigned short*)d_ws + 147456;   // 8 MB bf16 x

    prep_kernel<<<144 + 2048, 256, 0, stream>>>(Wk, Wt, x, xb);
    deform_kernel<<<(8 * 64 * 64) / TM, NT, 0, stream>>>(xb, off, Wt, bias, out);
}